// Round 1
// baseline (384.943 us; speedup 1.0000x reference)
//
#include <hip/hip_runtime.h>
#include <hip/hip_bf16.h>

// Dims (fixed for this problem)
#define BB 2
#define LL 1024
#define DMODEL 1024
#define DINNER 2048
#define DSTATE 16
#define DCONV 4
#define MM (BB * LL)          // 2048
#define N_XZ 4096
#define N_SSM 2080
#define N_SSM_PAD 2176        // 34 * 64
#define CCH 32                // chunks over L
#define LCH 32                // chunk length (CCH*LCH == LL)

typedef __hip_bfloat16 bf16;
typedef short bf16x8 __attribute__((ext_vector_type(8)));
typedef float f32x4 __attribute__((ext_vector_type(4)));

// ---------------- async global -> LDS, 16B per lane ----------------
__device__ __forceinline__ void load16_lds(const bf16* g, bf16* l) {
    __builtin_amdgcn_global_load_lds(
        (const __attribute__((address_space(1))) void*)g,
        (__attribute__((address_space(3))) void*)l,
        16, 0, 0);
}

// ---------------- fused prep: 4 weight transposes (f32[K,N] -> bf16[N,K]) + x cvt ----
__global__ __launch_bounds__(256) void prep_kernel(
    const float* __restrict__ x, bf16* __restrict__ xbf,
    const float* __restrict__ w1, bf16* __restrict__ o1,
    const float* __restrict__ w2, bf16* __restrict__ o2,
    const float* __restrict__ w3, bf16* __restrict__ o3,
    const float* __restrict__ w4, bf16* __restrict__ o4)
{
    int bid = blockIdx.x;
    const float* src; bf16* dst; int K, N, tn, tk;
    if (bid < 4096)        { src = w1; dst = o1; K = 1024; N = 4096; tn = bid & 127; tk = bid >> 7; }
    else if (bid < 8256)   { bid -= 4096;  src = w2; dst = o2; K = 2048; N = 2080; tn = bid % 65; tk = bid / 65; }
    else if (bid < 12352)  { bid -= 8256;  src = w3; dst = o3; K = 2048; N = 2048; tn = bid & 63; tk = bid >> 6; }
    else if (bid < 14400)  { bid -= 12352; src = w4; dst = o4; K = 2048; N = 1024; tn = bid & 31; tk = bid >> 5; }
    else {
        bid -= 14400;   // cvt: 2048 blocks x 1024 elems
        int i = (bid * 256 + threadIdx.x) * 4;
        float4 v = *(const float4*)(x + i);
        xbf[i + 0] = __float2bfloat16(v.x);
        xbf[i + 1] = __float2bfloat16(v.y);
        xbf[i + 2] = __float2bfloat16(v.z);
        xbf[i + 3] = __float2bfloat16(v.w);
        return;
    }
    __shared__ float tile[32][33];
    const int nb = tn * 32, kb = tk * 32;
    const int tx = threadIdx.x & 31, ty = threadIdx.x >> 5;
    #pragma unroll
    for (int i = 0; i < 32; i += 8) {
        int k = kb + ty + i, n = nb + tx;
        tile[ty + i][tx] = (k < K && n < N) ? src[(size_t)k * N + n] : 0.f;
    }
    __syncthreads();
    #pragma unroll
    for (int i = 0; i < 32; i += 8) {
        int n = nb + ty + i, k = kb + tx;
        if (n < N && k < K) dst[(size_t)n * K + k] = __float2bfloat16(tile[tx][ty + i]);
    }
}

// ---------------- MFMA GEMM v7: 128x64, TK=64, 2 waves x (64x64 wave tile) ------
// Wave tile 64x64 (acc[4][4]) doubles FLOP per LDS byte vs the old 4-wave 64x32:
// per K-step per wave 16 ds_read_b128 -> 32 MFMAs (was 12 -> 16).
// C[M,N] = A[M,K](bf16) @ Wt[N,K](bf16)^T
// EPI: 0 = bf16 store (col<N guard), 1 = +bias softplus f32, 2 = f32 (atomic if KSPLIT>1),
//      3 = cols<32 -> f32 BC sideband, cols in [32,N) -> bf16
// SWZ >= 0: XCD-aware remap, SWZ = log2(NX/8) (requires NX % 8 == 0, NX/8 pow2)
#define TM 128
#define TN 64
#define TK 64
template<int EPI, int KSPLIT = 1, int SWZ = -1>
__global__ __launch_bounds__(128) void mfma_gemm(
    const bf16* __restrict__ A, int lda,
    const bf16* __restrict__ Wt, int ldw,
    float* __restrict__ Cf, bf16* __restrict__ Cb, int ldc,
    const float* __restrict__ bias,
    int N, int K)
{
    __shared__ __align__(16) bf16 As[2][TM * TK];   // 2 x 16 KB
    __shared__ __align__(16) bf16 Bs[2][TN * TK];   // 2 x 8 KB  (48 KB total)
    const int tid = threadIdx.x;
    const int wave = tid >> 6, lane = tid & 63;
    const int wm = wave * 64;                       // wave owns rows [wm, wm+64)

    int bx, by;
    if (SWZ >= 0) {
        // bind XCD (id&7) to a contiguous N-range: weights per XCD fit L2
        int id = blockIdx.x + (int)(gridDim.x * blockIdx.y);
        int xcd = id & 7, slot = id >> 3;
        bx = (xcd << SWZ) + (slot & ((1 << SWZ) - 1));
        by = slot >> SWZ;
    } else { bx = blockIdx.x; by = blockIdx.y; }
    const int m0 = by * TM, n0 = bx * TN;
    const int lm = lane & 15, kq = lane >> 4;

    // staging: lane covers row (lane>>3), swizzled chunk (lane&7)^row
    const int srow = lane >> 3;
    const int schunk = (lane & 7) ^ srow;
    const bf16* gA = A + (size_t)(m0 + wave * 64 + srow) * lda + schunk * 8;
    const bf16* gB = Wt + (size_t)(n0 + wave * 32 + srow) * ldw + schunk * 8;

    const int Kc = K / KSPLIT;
    const int kbeg = (KSPLIT > 1) ? blockIdx.z * Kc : 0;
    const int NK = Kc / TK;   // 16 or 32 (even)

    f32x4 acc[4][4] = {};
    const int fsw = (lm & 7);   // frag-read XOR key

    auto stage = [&](int buf, int it) {
        const int k0 = kbeg + it * TK;
        bf16* lA = &As[buf][(wave * 64) * TK];      // wave stages its own 64 A-rows
        bf16* lB = &Bs[buf][(wave * 32) * TK];      // and half the B-rows
        #pragma unroll
        for (int g = 0; g < 8; ++g)
            load16_lds(gA + (size_t)(8 * g) * lda + k0, lA + (8 * g) * TK);
        #pragma unroll
        for (int g = 0; g < 4; ++g)
            load16_lds(gB + (size_t)(8 * g) * ldw + k0, lB + (8 * g) * TK);
    };  // 12 loads in flight per stage
    auto compute = [&](int buf) {
        bf16x8 af[4][2], bfr[4][2];
        #pragma unroll
        for (int i = 0; i < 4; ++i)
            #pragma unroll
            for (int t = 0; t < 2; ++t)
                af[i][t] = *(const bf16x8*)(&As[buf][(wm + i * 16 + lm) * TK + ((t * 4 + kq) ^ fsw) * 8]);
        #pragma unroll
        for (int j = 0; j < 4; ++j)
            #pragma unroll
            for (int t = 0; t < 2; ++t)
                bfr[j][t] = *(const bf16x8*)(&Bs[buf][(j * 16 + lm) * TK + ((t * 4 + kq) ^ fsw) * 8]);
        #pragma unroll
        for (int t = 0; t < 2; ++t)
            #pragma unroll
            for (int i = 0; i < 4; ++i)
                #pragma unroll
                for (int j = 0; j < 4; ++j)
                    acc[i][j] = __builtin_amdgcn_mfma_f32_16x16x32_bf16(af[i][t], bfr[j][t], acc[i][j], 0, 0, 0);
    };

    stage(0, 0);                                  // 12 loads in flight
    for (int it = 0; it < NK; it += 2) {
        stage(1, it + 1);                         // 24 in flight
        __builtin_amdgcn_s_waitcnt(0x0F7C);       // vmcnt(12): buf0 done, buf1 flying
        __builtin_amdgcn_s_barrier();
        compute(0);
        __builtin_amdgcn_s_barrier();             // everyone done reading buf0
        if (it + 2 < NK) {
            stage(0, it + 2);
            __builtin_amdgcn_s_waitcnt(0x0F7C);   // buf1 done, buf0 flying
        } else {
            __builtin_amdgcn_s_waitcnt(0x0F70);   // vmcnt(0)
        }
        __builtin_amdgcn_s_barrier();
        compute(1);
        __builtin_amdgcn_s_barrier();
    }

    // D layout: col = lane&15, row = (lane>>4)*4 + r (m89-verified)
    #pragma unroll
    for (int i = 0; i < 4; ++i) {
        #pragma unroll
        for (int j = 0; j < 4; ++j) {
            int gcol = n0 + j * 16 + lm;
            if ((EPI == 0 || EPI == 3) && gcol >= N) continue;
            #pragma unroll
            for (int r = 0; r < 4; ++r) {
                int grow = m0 + wm + i * 16 + kq * 4 + r;
                float v = acc[i][j][r];
                if (EPI == 1) {
                    v += bias[gcol];
                    v = (v > 20.f) ? v : log1pf(__expf(v));
                    Cf[(size_t)grow * ldc + gcol] = v;
                } else if (EPI == 2) {
                    if (KSPLIT > 1) atomicAdd(&Cf[(size_t)grow * ldc + gcol], v);
                    else            Cf[(size_t)grow * ldc + gcol] = v;
                } else if (EPI == 3) {
                    if (gcol < 32) Cf[(size_t)grow * 32 + gcol] = v;     // BC f32 sideband
                    else           Cb[(size_t)grow * ldc + gcol] = __float2bfloat16(v);
                } else {
                    Cb[(size_t)grow * ldc + gcol] = __float2bfloat16(v);
                }
            }
        }
    }
}

// ---------------- depthwise causal conv (k=4) + bias + SiLU (bf16 io, 8 ch/thread) ----
__global__ void conv_silu_kernel(const bf16* __restrict__ xz,
                                 const float* __restrict__ conv_w,
                                 const float* __restrict__ conv_b,
                                 bf16* __restrict__ u)
{
    int idx = blockIdx.x * blockDim.x + threadIdx.x;   // over BB*LL*DINNER/8
    int d8 = idx & (DINNER / 8 - 1);
    int l  = (idx >> 8) & (LL - 1);
    int b  = idx >> 18;
    int d0 = d8 * 8;

    float acc[8];
    {
        float4 b0 = *(const float4*)(conv_b + d0);
        float4 b1 = *(const float4*)(conv_b + d0 + 4);
        acc[0] = b0.x; acc[1] = b0.y; acc[2] = b0.z; acc[3] = b0.w;
        acc[4] = b1.x; acc[5] = b1.y; acc[6] = b1.z; acc[7] = b1.w;
    }
    #pragma unroll
    for (int j = 0; j < DCONV; ++j) {
        int ll = l - (DCONV - 1) + j;
        if (ll >= 0) {
            bf16x8 v = *(const bf16x8*)(xz + ((size_t)(b * LL + ll)) * N_XZ + d0);
            #pragma unroll
            for (int r = 0; r < 8; ++r) {
                float xv = __uint_as_float(((unsigned)(unsigned short)v[r]) << 16);
                acc[r] = fmaf(conv_w[(d0 + r) * DCONV + j], xv, acc[r]);
            }
        }
    }
    bf16x8 out;
    #pragma unroll
    for (int r = 0; r < 8; ++r) {
        float y = acc[r] / (1.f + __expf(-acc[r]));
        bf16 h = __float2bfloat16(y);
        out[r] = *reinterpret_cast<short*>(&h);
    }
    *(bf16x8*)(u + ((size_t)(b * LL + l)) * DINNER + d0) = out;
}

// ---------------- scan phase A: lane per (b,d,chunk), h[16] in regs ----------------
__global__ __launch_bounds__(256) void scan_phase_a(
    const float* __restrict__ dt, const bf16* __restrict__ u,
    const float* __restrict__ BC,    // (B,L,32) f32: B=[0:16), C=[16:32)
    const float* __restrict__ A_log,
    float* __restrict__ chunkP, float* __restrict__ chunkH)
{
    const int d = blockIdx.x * 256 + threadIdx.x;
    const int c = blockIdx.y, b = blockIdx.z;
    const int l0 = c * LCH;

    float A[DSTATE];
    {
        const f32x4* ap = (const f32x4*)(A_log + d * DSTATE);
        #pragma unroll
        for (int q = 0; q < 4; ++q) {
            f32x4 v = ap[q];
            #pragma unroll
            for (int r = 0; r < 4; ++r) A[q * 4 + r] = -__expf(v[r]);
        }
    }
    float h[DSTATE];
    #pragma unroll
    for (int n = 0; n < DSTATE; ++n) h[n] = 0.f;
    float sdt = 0.f;

    const float* dtp = dt + ((size_t)b * LL + l0) * DINNER + d;
    const bf16* up = u + ((size_t)b * LL + l0) * DINNER + d;
    const float* bcp = BC + ((size_t)b * LL + l0) * 32;

    #pragma unroll 2
    for (int i = 0; i < LCH; ++i) {
        float dtv = *dtp;
        float uv  = (float)*up;
        float du  = dtv * uv;
        f32x4 Bv[4];
        #pragma unroll
        for (int q = 0; q < 4; ++q) Bv[q] = *(const f32x4*)(bcp + q * 4);
        #pragma unroll
        for (int n = 0; n < DSTATE; ++n) {
            float a = __expf(dtv * A[n]);
            h[n] = fmaf(a, h[n], du * Bv[n >> 2][n & 3]);
        }
        sdt += dtv;
        dtp += DINNER; up += DINNER; bcp += 32;
    }

    size_t idx = (((size_t)b * CCH + c) * DINNER + d) * DSTATE;
    #pragma unroll
    for (int q = 0; q < 4; ++q) {
        f32x4 pv, hv;
        #pragma unroll
        for (int r = 0; r < 4; ++r) { pv[r] = __expf(A[q * 4 + r] * sdt); hv[r] = h[q * 4 + r]; }
        *(f32x4*)(chunkP + idx + q * 4) = pv;
        *(f32x4*)(chunkH + idx + q * 4) = hv;
    }
}

// ---------------- scan phase P: exclusive prefix over chunks, in place on chunkH ----
__global__ __launch_bounds__(256) void scan_phase_p(
    const float* __restrict__ chunkP, float* __restrict__ chunkH)
{
    int gid = blockIdx.x * 256 + threadIdx.x;   // over B*DINNER*DSTATE = 65536
    int n = gid & 15;
    int d = (gid >> 4) & (DINNER - 1);
    int b = gid >> 15;
    const size_t stride = (size_t)DINNER * DSTATE;
    size_t idx = ((size_t)b * CCH * DINNER + d) * DSTATE + n;
    float H = 0.f;
    for (int c = 0; c < CCH; ++c) {
        float P  = chunkP[idx];
        float hl = chunkH[idx];
        chunkH[idx] = H;           // exclusive prefix
        H = fmaf(P, H, hl);
        idx += stride;
    }
}

// ---------------- scan phase B: lane per (b,d,chunk); gated y over u --------
__global__ __launch_bounds__(256) void scan_phase_b(
    const float* __restrict__ dt, bf16* __restrict__ u,
    const float* __restrict__ BC, const bf16* __restrict__ xz,
    const float* __restrict__ A_log, const float* __restrict__ Dp,
    const float* __restrict__ chunkH)
{
    const int d = blockIdx.x * 256 + threadIdx.x;
    const int c = blockIdx.y, b = blockIdx.z;
    const int l0 = c * LCH;

    float A[DSTATE];
    {
        const f32x4* ap = (const f32x4*)(A_log + d * DSTATE);
        #pragma unroll
        for (int q = 0; q < 4; ++q) {
            f32x4 v = ap[q];
            #pragma unroll
            for (int r = 0; r < 4; ++r) A[q * 4 + r] = -__expf(v[r]);
        }
    }
    const float Dd = Dp[d];
    float h[DSTATE];
    {
        size_t idx = (((size_t)b * CCH + c) * DINNER + d) * DSTATE;
        #pragma unroll
        for (int q = 0; q < 4; ++q) {
            f32x4 v = *(const f32x4*)(chunkH + idx + q * 4);
            #pragma unroll
            for (int r = 0; r < 4; ++r) h[q * 4 + r] = v[r];
        }
    }

    const float* dtp = dt + ((size_t)b * LL + l0) * DINNER + d;
    bf16* up = u + ((size_t)b * LL + l0) * DINNER + d;
    const float* bcp = BC + ((size_t)b * LL + l0) * 32;
    const bf16* zp = xz + ((size_t)b * LL + l0) * N_XZ + DINNER + d;

    #pragma unroll 2
    for (int i = 0; i < LCH; ++i) {
        float dtv = *dtp;
        float uv  = (float)*up;
        float du  = dtv * uv;
        f32x4 Bv[4], Cv[4];
        #pragma unroll
        for (int q = 0; q < 4; ++q) {
            Bv[q] = *(const f32x4*)(bcp + q * 4);
            Cv[q] = *(const f32x4*)(bcp + 16 + q * 4);
        }
        float acc = 0.f;
        #pragma unroll
        for (int n = 0; n < DSTATE; ++n) {
            float a = __expf(dtv * A[n]);
            h[n] = fmaf(a, h[n], du * Bv[n >> 2][n & 3]);
            acc = fmaf(h[n], Cv[n >> 2][n & 3], acc);
        }
        float zv = (float)*zp;
        acc = fmaf(Dd, uv, acc);
        acc *= zv / (1.f + __expf(-zv));
        *up = __float2bfloat16(acc);
        dtp += DINNER; up += DINNER; bcp += 32; zp += N_XZ;
    }
}

extern "C" void kernel_launch(void* const* d_in, const int* in_sizes, int n_in,
                              void* d_out, int out_size, void* d_ws, size_t ws_size,
                              hipStream_t stream) {
    const float* x         = (const float*)d_in[0];
    const float* in_proj_w = (const float*)d_in[1];
    const float* conv_w    = (const float*)d_in[2];
    const float* conv_b    = (const float*)d_in[3];
    const float* x_proj_w  = (const float*)d_in[4];
    const float* dt_proj_w = (const float*)d_in[5];
    const float* dt_proj_b = (const float*)d_in[6];
    const float* A_log     = (const float*)d_in[7];
    const float* Dp        = (const float*)d_in[8];
    const float* out_proj_w= (const float*)d_in[9];
    float* out = (float*)d_out;

    // workspace layout (~80.7 MB); xbf aliases dt; chunkP/H alias Wt1/Wt2
    char* p = (char*)d_ws;
    float* dt   = (float*)p;                          p += (size_t)MM * DINNER * 4;
    bf16*  xbf  = (bf16*)dt;
    bf16*  xz   = (bf16*)p;                           p += (size_t)MM * N_XZ * 2;
    bf16*  u    = (bf16*)p;                           p += (size_t)MM * DINNER * 2;
    bf16*  ssm  = (bf16*)p;                           p += (size_t)MM * N_SSM * 2;
    bf16*  Wt1  = (bf16*)p;                           p += (size_t)N_XZ * DMODEL * 2;      // 8 MB
    bf16*  Wt2  = (bf16*)p;                           p += (size_t)N_SSM_PAD * DINNER * 2; // 8.9 MB
    bf16*  Wt3  = (bf16*)p;                           p += (size_t)DINNER * DINNER * 2;
    bf16*  Wt4  = (bf16*)p;                           p += (size_t)DMODEL * DINNER * 2;
    float* BC   = (float*)p;                          p += (size_t)MM * 32 * 4;            // 256 KB
    float* chunkP = (float*)Wt1;   // B*CCH*DINNER*16 f32 = 8 MB exactly
    float* chunkH = (float*)Wt2;   // 8 MB of Wt2's 8.9

    // 0) fused prep: 4 transposes + x cvt in one launch
    prep_kernel<<<16448, 256, 0, stream>>>(x, xbf, in_proj_w, Wt1, x_proj_w, Wt2,
                                           dt_proj_w, Wt3, out_proj_w, Wt4);
    // 1) xz = xbf @ W1   (2048 x 4096, K=1024) — 1024 blocks, SWZ: 8 n-tiles/XCD
    mfma_gemm<0, 1, 3><<<dim3(N_XZ / TN, MM / TM), 128, 0, stream>>>(
        xbf, DMODEL, Wt1, DMODEL, nullptr, xz, N_XZ, nullptr, N_XZ, DMODEL);
    // 2) u = silu(conv(x_inner)+b)  — 8 channels/thread, bf16x8 io
    {
        int n = BB * LL * DINNER / 8;
        conv_silu_kernel<<<(n + 255) / 256, 256, 0, stream>>>(xz, conv_w, conv_b, u);
    }
    // 3) ssm = u @ W2    (2048 x 2080, K=2048); cols<32 -> BC f32 — 544 blocks, no SWZ
    mfma_gemm<3><<<dim3(N_SSM_PAD / TN, MM / TM), 128, 0, stream>>>(
        u, DINNER, Wt2, DINNER, BC, ssm, N_SSM, nullptr, N_SSM, DINNER);
    // 4) dt = softplus(ssm[:,32:] @ W3 + b)  (2048 x 2048) — 512 blocks, SWZ: 4 n-tiles/XCD
    mfma_gemm<1, 1, 2><<<dim3(DINNER / TN, MM / TM), 128, 0, stream>>>(
        ssm + 2 * DSTATE, N_SSM, Wt3, DINNER, dt, nullptr, DINNER, dt_proj_b, DINNER, DINNER);
    // 5) chunked selective scan: A (local), P (prefix), B (apply; y over u)
    scan_phase_a<<<dim3(DINNER / 256, CCH, BB), 256, 0, stream>>>(dt, u, BC, A_log, chunkP, chunkH);
    scan_phase_p<<<dim3(BB * DINNER * DSTATE / 256), 256, 0, stream>>>(chunkP, chunkH);
    scan_phase_b<<<dim3(DINNER / 256, CCH, BB), 256, 0, stream>>>(dt, u, BC, xz, A_log, Dp, chunkH);
    // 6) out = y @ W4    (2048 x 1024, K=2048), split-K=2 atomic — 512 blocks, SWZ
    hipMemsetAsync(out, 0, (size_t)out_size * sizeof(float), stream);
    mfma_gemm<2, 2, 1><<<dim3(DMODEL / TN, MM / TM, 2), 128, 0, stream>>>(
        u, DINNER, Wt4, DINNER, out, nullptr, DMODEL, nullptr, DMODEL, DINNER);
}

// Round 2
// 363.436 us; speedup vs baseline: 1.0592x; 1.0592x over previous
//
#include <hip/hip_runtime.h>
#include <hip/hip_bf16.h>

// Dims (fixed for this problem)
#define BB 2
#define LL 1024
#define DMODEL 1024
#define DINNER 2048
#define DSTATE 16
#define DCONV 4
#define MM (BB * LL)          // 2048
#define N_XZ 4096
#define N_SSM 2080
#define N_SSM_PAD 2176        // 34 * 64
#define CCH 32                // chunks over L
#define LCH 32                // chunk length (CCH*LCH == LL)

typedef __hip_bfloat16 bf16;
typedef short bf16x8 __attribute__((ext_vector_type(8)));
typedef float f32x4 __attribute__((ext_vector_type(4)));

// ---------------- async global -> LDS, 16B per lane ----------------
__device__ __forceinline__ void load16_lds(const bf16* g, bf16* l) {
    __builtin_amdgcn_global_load_lds(
        (const __attribute__((address_space(1))) void*)g,
        (__attribute__((address_space(3))) void*)l,
        16, 0, 0);
}

// ---------------- fused prep: 4 weight transposes (f32[K,N] -> bf16[N,K]) + x cvt ----
__global__ __launch_bounds__(256) void prep_kernel(
    const float* __restrict__ x, bf16* __restrict__ xbf,
    const float* __restrict__ w1, bf16* __restrict__ o1,
    const float* __restrict__ w2, bf16* __restrict__ o2,
    const float* __restrict__ w3, bf16* __restrict__ o3,
    const float* __restrict__ w4, bf16* __restrict__ o4)
{
    int bid = blockIdx.x;
    const float* src; bf16* dst; int K, N, tn, tk;
    if (bid < 4096)        { src = w1; dst = o1; K = 1024; N = 4096; tn = bid & 127; tk = bid >> 7; }
    else if (bid < 8256)   { bid -= 4096;  src = w2; dst = o2; K = 2048; N = 2080; tn = bid % 65; tk = bid / 65; }
    else if (bid < 12352)  { bid -= 8256;  src = w3; dst = o3; K = 2048; N = 2048; tn = bid & 63; tk = bid >> 6; }
    else if (bid < 14400)  { bid -= 12352; src = w4; dst = o4; K = 2048; N = 1024; tn = bid & 31; tk = bid >> 5; }
    else {
        bid -= 14400;   // cvt: 2048 blocks x 1024 elems
        int i = (bid * 256 + threadIdx.x) * 4;
        float4 v = *(const float4*)(x + i);
        xbf[i + 0] = __float2bfloat16(v.x);
        xbf[i + 1] = __float2bfloat16(v.y);
        xbf[i + 2] = __float2bfloat16(v.z);
        xbf[i + 3] = __float2bfloat16(v.w);
        return;
    }
    __shared__ float tile[32][33];
    const int nb = tn * 32, kb = tk * 32;
    const int tx = threadIdx.x & 31, ty = threadIdx.x >> 5;
    #pragma unroll
    for (int i = 0; i < 32; i += 8) {
        int k = kb + ty + i, n = nb + tx;
        tile[ty + i][tx] = (k < K && n < N) ? src[(size_t)k * N + n] : 0.f;
    }
    __syncthreads();
    #pragma unroll
    for (int i = 0; i < 32; i += 8) {
        int n = nb + ty + i, k = kb + tx;
        if (n < N && k < K) dst[(size_t)n * K + k] = __float2bfloat16(tile[tx][ty + i]);
    }
}

// ---------------- MFMA GEMM v8: 128x64, TK=64, 4 waves x (64x32), 3-deep pipeline ---
// v6 compute geometry (proven 48us) + NBUF=3 LDS pipeline: loads issued 3 iters
// ahead, counted vmcnt(12) steady-state (never drain mid-loop). Slack between a
// buffer's load-issue and its consume = 2 full iterations (~1000+ cyc) -> covers
// HBM latency; v6 only had depth-1 (~1 compute phase of slack).
// C[M,N] = A[M,K](bf16) @ Wt[N,K](bf16)^T
// EPI: 0 = bf16 store (col<N guard), 1 = +bias softplus f32, 2 = f32 (atomic if KSPLIT>1),
//      3 = cols<32 -> f32 BC sideband, cols in [32,N) -> bf16
// SWZ >= 0: XCD-aware remap, SWZ = log2(NX/8) (requires NX % 8 == 0, NX/8 pow2)
#define TM 128
#define TN 64
#define TK 64
template<int EPI, int KSPLIT = 1, int SWZ = -1>
__global__ __launch_bounds__(256) void mfma_gemm(
    const bf16* __restrict__ A, int lda,
    const bf16* __restrict__ Wt, int ldw,
    float* __restrict__ Cf, bf16* __restrict__ Cb, int ldc,
    const float* __restrict__ bias,
    int N, int K)
{
    __shared__ __align__(16) bf16 As[3][TM * TK];   // 3 x 16 KB
    __shared__ __align__(16) bf16 Bs[3][TN * TK];   // 3 x 8 KB  (72 KB total, 2 blk/CU)
    const int tid = threadIdx.x;
    const int wave = tid >> 6, lane = tid & 63;
    const int wm = (wave >> 1) * 64, wn = (wave & 1) * 32;

    int bx, by;
    if (SWZ >= 0) {
        // bind XCD (id&7) to a contiguous N-range: weights per XCD fit L2
        int id = blockIdx.x + (int)(gridDim.x * blockIdx.y);
        int xcd = id & 7, slot = id >> 3;
        bx = (xcd << SWZ) + (slot & ((1 << SWZ) - 1));
        by = slot >> SWZ;
    } else { bx = blockIdx.x; by = blockIdx.y; }
    const int m0 = by * TM, n0 = bx * TN;
    const int lm = lane & 15, kq = lane >> 4;

    // staging: lane covers row (lane>>3), swizzled chunk (lane&7)^row
    const int srow = lane >> 3;
    const int schunk = (lane & 7) ^ srow;
    const bf16* gA = A + (size_t)(m0 + wave * 32 + srow) * lda + schunk * 8;
    const bf16* gB = Wt + (size_t)(n0 + wave * 16 + srow) * ldw + schunk * 8;

    const int Kc = K / KSPLIT;
    const int kbeg = (KSPLIT > 1) ? blockIdx.z * Kc : 0;
    const int NK = Kc / TK;   // 16 or 32

    f32x4 acc[4][2] = {};
    const int fsw = (lm & 7);   // frag-read XOR key

    auto stage = [&](int buf, int it) {
        const int k0 = kbeg + it * TK;
        bf16* lA = &As[buf][(wave * 32) * TK];
        bf16* lB = &Bs[buf][(wave * 16) * TK];
        #pragma unroll
        for (int g = 0; g < 4; ++g)
            load16_lds(gA + (size_t)(8 * g) * lda + k0, lA + (8 * g) * TK);
        #pragma unroll
        for (int g = 0; g < 2; ++g)
            load16_lds(gB + (size_t)(8 * g) * ldw + k0, lB + (8 * g) * TK);
    };  // 6 loads per wave per stage
    auto compute = [&](int buf) {
        bf16x8 af[4][2], bfr[2][2];
        #pragma unroll
        for (int i = 0; i < 4; ++i)
            #pragma unroll
            for (int t = 0; t < 2; ++t)
                af[i][t] = *(const bf16x8*)(&As[buf][(wm + i * 16 + lm) * TK + ((t * 4 + kq) ^ fsw) * 8]);
        #pragma unroll
        for (int j = 0; j < 2; ++j)
            #pragma unroll
            for (int t = 0; t < 2; ++t)
                bfr[j][t] = *(const bf16x8*)(&Bs[buf][(wn + j * 16 + lm) * TK + ((t * 4 + kq) ^ fsw) * 8]);
        #pragma unroll
        for (int t = 0; t < 2; ++t)
            #pragma unroll
            for (int i = 0; i < 4; ++i)
                #pragma unroll
                for (int j = 0; j < 2; ++j)
                    acc[i][j] = __builtin_amdgcn_mfma_f32_16x16x32_bf16(af[i][t], bfr[j][t], acc[i][j], 0, 0, 0);
    };

    // 3-deep prologue: 18 loads in flight per wave
    stage(0, 0); stage(1, 1); stage(2, 2);
    for (int it = 0; it < NK; ++it) {
        // wait for buf[it%3]'s 6 loads (oldest). Steady: 18 outstanding -> vmcnt(12).
        if (it + 2 < NK)      __builtin_amdgcn_s_waitcnt(0x0F7C);   // vmcnt(12)
        else if (it + 1 < NK) __builtin_amdgcn_s_waitcnt(0x0F76);   // vmcnt(6)
        else                  __builtin_amdgcn_s_waitcnt(0x0F70);   // vmcnt(0)
        __builtin_amdgcn_s_barrier();          // all waves' loads for buf landed
        const int buf = it % 3;
        compute(buf);
        __builtin_amdgcn_s_barrier();          // all waves done reading buf
        if (it + 3 < NK) stage(buf, it + 3);   // refill: consumed 2 iters from now
    }

    // D layout: col = lane&15, row = (lane>>4)*4 + r (m89-verified)
    #pragma unroll
    for (int i = 0; i < 4; ++i) {
        #pragma unroll
        for (int j = 0; j < 2; ++j) {
            int gcol = n0 + wn + j * 16 + lm;
            if ((EPI == 0 || EPI == 3) && gcol >= N) continue;
            #pragma unroll
            for (int r = 0; r < 4; ++r) {
                int grow = m0 + wm + i * 16 + kq * 4 + r;
                float v = acc[i][j][r];
                if (EPI == 1) {
                    v += bias[gcol];
                    v = (v > 20.f) ? v : log1pf(__expf(v));
                    Cf[(size_t)grow * ldc + gcol] = v;
                } else if (EPI == 2) {
                    if (KSPLIT > 1) atomicAdd(&Cf[(size_t)grow * ldc + gcol], v);
                    else            Cf[(size_t)grow * ldc + gcol] = v;
                } else if (EPI == 3) {
                    if (gcol < 32) Cf[(size_t)grow * 32 + gcol] = v;     // BC f32 sideband
                    else           Cb[(size_t)grow * ldc + gcol] = __float2bfloat16(v);
                } else {
                    Cb[(size_t)grow * ldc + gcol] = __float2bfloat16(v);
                }
            }
        }
    }
}

// ---------------- depthwise causal conv (k=4) + bias + SiLU (bf16 io, 8 ch/thread) ----
__global__ void conv_silu_kernel(const bf16* __restrict__ xz,
                                 const float* __restrict__ conv_w,
                                 const float* __restrict__ conv_b,
                                 bf16* __restrict__ u)
{
    int idx = blockIdx.x * blockDim.x + threadIdx.x;   // over BB*LL*DINNER/8
    int d8 = idx & (DINNER / 8 - 1);
    int l  = (idx >> 8) & (LL - 1);
    int b  = idx >> 18;
    int d0 = d8 * 8;

    float acc[8];
    {
        float4 b0 = *(const float4*)(conv_b + d0);
        float4 b1 = *(const float4*)(conv_b + d0 + 4);
        acc[0] = b0.x; acc[1] = b0.y; acc[2] = b0.z; acc[3] = b0.w;
        acc[4] = b1.x; acc[5] = b1.y; acc[6] = b1.z; acc[7] = b1.w;
    }
    #pragma unroll
    for (int j = 0; j < DCONV; ++j) {
        int ll = l - (DCONV - 1) + j;
        if (ll >= 0) {
            bf16x8 v = *(const bf16x8*)(xz + ((size_t)(b * LL + ll)) * N_XZ + d0);
            #pragma unroll
            for (int r = 0; r < 8; ++r) {
                float xv = __uint_as_float(((unsigned)(unsigned short)v[r]) << 16);
                acc[r] = fmaf(conv_w[(d0 + r) * DCONV + j], xv, acc[r]);
            }
        }
    }
    bf16x8 out;
    #pragma unroll
    for (int r = 0; r < 8; ++r) {
        float y = acc[r] / (1.f + __expf(-acc[r]));
        bf16 h = __float2bfloat16(y);
        out[r] = *reinterpret_cast<short*>(&h);
    }
    *(bf16x8*)(u + ((size_t)(b * LL + l)) * DINNER + d0) = out;
}

// ---------------- scan phase A: lane per (b,d,chunk), h[16] in regs ----------------
__global__ __launch_bounds__(256) void scan_phase_a(
    const float* __restrict__ dt, const bf16* __restrict__ u,
    const float* __restrict__ BC,    // (B,L,32) f32: B=[0:16), C=[16:32)
    const float* __restrict__ A_log,
    float* __restrict__ chunkP, float* __restrict__ chunkH)
{
    const int d = blockIdx.x * 256 + threadIdx.x;
    const int c = blockIdx.y, b = blockIdx.z;
    const int l0 = c * LCH;

    float A[DSTATE];
    {
        const f32x4* ap = (const f32x4*)(A_log + d * DSTATE);
        #pragma unroll
        for (int q = 0; q < 4; ++q) {
            f32x4 v = ap[q];
            #pragma unroll
            for (int r = 0; r < 4; ++r) A[q * 4 + r] = -__expf(v[r]);
        }
    }
    float h[DSTATE];
    #pragma unroll
    for (int n = 0; n < DSTATE; ++n) h[n] = 0.f;
    float sdt = 0.f;

    const float* dtp = dt + ((size_t)b * LL + l0) * DINNER + d;
    const bf16* up = u + ((size_t)b * LL + l0) * DINNER + d;
    const float* bcp = BC + ((size_t)b * LL + l0) * 32;

    #pragma unroll 2
    for (int i = 0; i < LCH; ++i) {
        float dtv = *dtp;
        float uv  = (float)*up;
        float du  = dtv * uv;
        f32x4 Bv[4];
        #pragma unroll
        for (int q = 0; q < 4; ++q) Bv[q] = *(const f32x4*)(bcp + q * 4);
        #pragma unroll
        for (int n = 0; n < DSTATE; ++n) {
            float a = __expf(dtv * A[n]);
            h[n] = fmaf(a, h[n], du * Bv[n >> 2][n & 3]);
        }
        sdt += dtv;
        dtp += DINNER; up += DINNER; bcp += 32;
    }

    size_t idx = (((size_t)b * CCH + c) * DINNER + d) * DSTATE;
    #pragma unroll
    for (int q = 0; q < 4; ++q) {
        f32x4 pv, hv;
        #pragma unroll
        for (int r = 0; r < 4; ++r) { pv[r] = __expf(A[q * 4 + r] * sdt); hv[r] = h[q * 4 + r]; }
        *(f32x4*)(chunkP + idx + q * 4) = pv;
        *(f32x4*)(chunkH + idx + q * 4) = hv;
    }
}

// ---------------- scan phase P: exclusive prefix over chunks, in place on chunkH ----
__global__ __launch_bounds__(256) void scan_phase_p(
    const float* __restrict__ chunkP, float* __restrict__ chunkH)
{
    int gid = blockIdx.x * 256 + threadIdx.x;   // over B*DINNER*DSTATE = 65536
    int n = gid & 15;
    int d = (gid >> 4) & (DINNER - 1);
    int b = gid >> 15;
    const size_t stride = (size_t)DINNER * DSTATE;
    size_t idx = ((size_t)b * CCH * DINNER + d) * DSTATE + n;
    float H = 0.f;
    for (int c = 0; c < CCH; ++c) {
        float P  = chunkP[idx];
        float hl = chunkH[idx];
        chunkH[idx] = H;           // exclusive prefix
        H = fmaf(P, H, hl);
        idx += stride;
    }
}

// ---------------- scan phase B: lane per (b,d,chunk); gated y over u --------
__global__ __launch_bounds__(256) void scan_phase_b(
    const float* __restrict__ dt, bf16* __restrict__ u,
    const float* __restrict__ BC, const bf16* __restrict__ xz,
    const float* __restrict__ A_log, const float* __restrict__ Dp,
    const float* __restrict__ chunkH)
{
    const int d = blockIdx.x * 256 + threadIdx.x;
    const int c = blockIdx.y, b = blockIdx.z;
    const int l0 = c * LCH;

    float A[DSTATE];
    {
        const f32x4* ap = (const f32x4*)(A_log + d * DSTATE);
        #pragma unroll
        for (int q = 0; q < 4; ++q) {
            f32x4 v = ap[q];
            #pragma unroll
            for (int r = 0; r < 4; ++r) A[q * 4 + r] = -__expf(v[r]);
        }
    }
    const float Dd = Dp[d];
    float h[DSTATE];
    {
        size_t idx = (((size_t)b * CCH + c) * DINNER + d) * DSTATE;
        #pragma unroll
        for (int q = 0; q < 4; ++q) {
            f32x4 v = *(const f32x4*)(chunkH + idx + q * 4);
            #pragma unroll
            for (int r = 0; r < 4; ++r) h[q * 4 + r] = v[r];
        }
    }

    const float* dtp = dt + ((size_t)b * LL + l0) * DINNER + d;
    bf16* up = u + ((size_t)b * LL + l0) * DINNER + d;
    const float* bcp = BC + ((size_t)b * LL + l0) * 32;
    const bf16* zp = xz + ((size_t)b * LL + l0) * N_XZ + DINNER + d;

    #pragma unroll 2
    for (int i = 0; i < LCH; ++i) {
        float dtv = *dtp;
        float uv  = (float)*up;
        float du  = dtv * uv;
        f32x4 Bv[4], Cv[4];
        #pragma unroll
        for (int q = 0; q < 4; ++q) {
            Bv[q] = *(const f32x4*)(bcp + q * 4);
            Cv[q] = *(const f32x4*)(bcp + 16 + q * 4);
        }
        float acc = 0.f;
        #pragma unroll
        for (int n = 0; n < DSTATE; ++n) {
            float a = __expf(dtv * A[n]);
            h[n] = fmaf(a, h[n], du * Bv[n >> 2][n & 3]);
            acc = fmaf(h[n], Cv[n >> 2][n & 3], acc);
        }
        float zv = (float)*zp;
        acc = fmaf(Dd, uv, acc);
        acc *= zv / (1.f + __expf(-zv));
        *up = __float2bfloat16(acc);
        dtp += DINNER; up += DINNER; bcp += 32; zp += N_XZ;
    }
}

extern "C" void kernel_launch(void* const* d_in, const int* in_sizes, int n_in,
                              void* d_out, int out_size, void* d_ws, size_t ws_size,
                              hipStream_t stream) {
    const float* x         = (const float*)d_in[0];
    const float* in_proj_w = (const float*)d_in[1];
    const float* conv_w    = (const float*)d_in[2];
    const float* conv_b    = (const float*)d_in[3];
    const float* x_proj_w  = (const float*)d_in[4];
    const float* dt_proj_w = (const float*)d_in[5];
    const float* dt_proj_b = (const float*)d_in[6];
    const float* A_log     = (const float*)d_in[7];
    const float* Dp        = (const float*)d_in[8];
    const float* out_proj_w= (const float*)d_in[9];
    float* out = (float*)d_out;

    // workspace layout (~80.7 MB); xbf aliases dt; chunkP/H alias Wt1/Wt2
    char* p = (char*)d_ws;
    float* dt   = (float*)p;                          p += (size_t)MM * DINNER * 4;
    bf16*  xbf  = (bf16*)dt;
    bf16*  xz   = (bf16*)p;                           p += (size_t)MM * N_XZ * 2;
    bf16*  u    = (bf16*)p;                           p += (size_t)MM * DINNER * 2;
    bf16*  ssm  = (bf16*)p;                           p += (size_t)MM * N_SSM * 2;
    bf16*  Wt1  = (bf16*)p;                           p += (size_t)N_XZ * DMODEL * 2;      // 8 MB
    bf16*  Wt2  = (bf16*)p;                           p += (size_t)N_SSM_PAD * DINNER * 2; // 8.9 MB
    bf16*  Wt3  = (bf16*)p;                           p += (size_t)DINNER * DINNER * 2;
    bf16*  Wt4  = (bf16*)p;                           p += (size_t)DMODEL * DINNER * 2;
    float* BC   = (float*)p;                          p += (size_t)MM * 32 * 4;            // 256 KB
    float* chunkP = (float*)Wt1;   // B*CCH*DINNER*16 f32 = 8 MB exactly
    float* chunkH = (float*)Wt2;   // 8 MB of Wt2's 8.9

    // 0) fused prep: 4 transposes + x cvt in one launch
    prep_kernel<<<16448, 256, 0, stream>>>(x, xbf, in_proj_w, Wt1, x_proj_w, Wt2,
                                           dt_proj_w, Wt3, out_proj_w, Wt4);
    // 1) xz = xbf @ W1   (2048 x 4096, K=1024) — 1024 blocks, SWZ: 8 n-tiles/XCD
    mfma_gemm<0, 1, 3><<<dim3(N_XZ / TN, MM / TM), 256, 0, stream>>>(
        xbf, DMODEL, Wt1, DMODEL, nullptr, xz, N_XZ, nullptr, N_XZ, DMODEL);
    // 2) u = silu(conv(x_inner)+b)  — 8 channels/thread, bf16x8 io
    {
        int n = BB * LL * DINNER / 8;
        conv_silu_kernel<<<(n + 255) / 256, 256, 0, stream>>>(xz, conv_w, conv_b, u);
    }
    // 3) ssm = u @ W2    (2048 x 2080, K=2048); cols<32 -> BC f32 — 544 blocks, no SWZ
    mfma_gemm<3><<<dim3(N_SSM_PAD / TN, MM / TM), 256, 0, stream>>>(
        u, DINNER, Wt2, DINNER, BC, ssm, N_SSM, nullptr, N_SSM, DINNER);
    // 4) dt = softplus(ssm[:,32:] @ W3 + b)  (2048 x 2048) — 512 blocks, SWZ: 4 n-tiles/XCD
    mfma_gemm<1, 1, 2><<<dim3(DINNER / TN, MM / TM), 256, 0, stream>>>(
        ssm + 2 * DSTATE, N_SSM, Wt3, DINNER, dt, nullptr, DINNER, dt_proj_b, DINNER, DINNER);
    // 5) chunked selective scan: A (local), P (prefix), B (apply; y over u)
    scan_phase_a<<<dim3(DINNER / 256, CCH, BB), 256, 0, stream>>>(dt, u, BC, A_log, chunkP, chunkH);
    scan_phase_p<<<dim3(BB * DINNER * DSTATE / 256), 256, 0, stream>>>(chunkP, chunkH);
    scan_phase_b<<<dim3(DINNER / 256, CCH, BB), 256, 0, stream>>>(dt, u, BC, xz, A_log, Dp, chunkH);
    // 6) out = y @ W4    (2048 x 1024, K=2048), split-K=2 atomic — 512 blocks, SWZ
    hipMemsetAsync(out, 0, (size_t)out_size * sizeof(float), stream);
    mfma_gemm<2, 2, 1><<<dim3(DMODEL / TN, MM / TM, 2), 256, 0, stream>>>(
        u, DINNER, Wt4, DINNER, out, nullptr, DMODEL, nullptr, DMODEL, DINNER);
}

// Round 3
// 334.241 us; speedup vs baseline: 1.1517x; 1.0873x over previous
//
#include <hip/hip_runtime.h>
#include <hip/hip_bf16.h>

// Dims (fixed for this problem)
#define BB 2
#define LL 1024
#define DMODEL 1024
#define DINNER 2048
#define DSTATE 16
#define DCONV 4
#define MM (BB * LL)          // 2048
#define N_XZ 4096
#define N_SSM 2080
#define N_SSM_PAD 2176        // 34 * 64
#define CCH 32                // chunks over L
#define LCH 32                // chunk length (CCH*LCH == LL)

typedef __hip_bfloat16 bf16;
typedef short bf16x8 __attribute__((ext_vector_type(8)));
typedef float f32x4 __attribute__((ext_vector_type(4)));

// ---------------- async global -> LDS, 16B per lane ----------------
__device__ __forceinline__ void load16_lds(const bf16* g, bf16* l) {
    __builtin_amdgcn_global_load_lds(
        (const __attribute__((address_space(1))) void*)g,
        (__attribute__((address_space(3))) void*)l,
        16, 0, 0);
}

// ---------------- fused prep: 3 weight transposes + W2 cvt + BC-slice transpose + x cvt
// W2 is NOT transposed anymore: the fused Wf GEMM consumes it row-major (bf16 cvt),
// and only its first 32 cols (B,C projections) need a transpose (w2bc, 32x2048).
__global__ __launch_bounds__(256) void prep_kernel(
    const float* __restrict__ x, bf16* __restrict__ xbf,
    const float* __restrict__ w1, bf16* __restrict__ o1,
    const float* __restrict__ w3, bf16* __restrict__ o3,
    const float* __restrict__ w4, bf16* __restrict__ o4,
    const float* __restrict__ w2, bf16* __restrict__ w2bf,
    bf16* __restrict__ w2bc)
{
    int bid = blockIdx.x;
    if (bid >= 14464) {                 // x cvt: 2048 blocks x 1024 elems
        bid -= 14464;
        int i = (bid * 256 + threadIdx.x) * 4;
        float4 v = *(const float4*)(x + i);
        xbf[i + 0] = __float2bfloat16(v.x);
        xbf[i + 1] = __float2bfloat16(v.y);
        xbf[i + 2] = __float2bfloat16(v.z);
        xbf[i + 3] = __float2bfloat16(v.w);
        return;
    }
    if (bid >= 10240 && bid < 14400) {  // w2 cvt: 2048*2080 f32 -> bf16, 4160 blocks
        bid -= 10240;
        int i = (bid * 256 + threadIdx.x) * 4;
        float4 v = *(const float4*)(w2 + i);
        w2bf[i + 0] = __float2bfloat16(v.x);
        w2bf[i + 1] = __float2bfloat16(v.y);
        w2bf[i + 2] = __float2bfloat16(v.z);
        w2bf[i + 3] = __float2bfloat16(v.w);
        return;
    }
    const float* src; bf16* dst; int K, N, tn, tk, srcld;
    if (bid < 4096)        { src = w1; dst = o1; K = 1024; N = 4096; tn = bid & 127; tk = bid >> 7; srcld = N; }
    else if (bid < 8192)   { bid -= 4096; src = w3; dst = o3; K = 2048; N = 2048; tn = bid & 63; tk = bid >> 6; srcld = N; }
    else if (bid < 10240)  { bid -= 8192; src = w4; dst = o4; K = 2048; N = 1024; tn = bid & 31; tk = bid >> 5; srcld = N; }
    else                   { bid -= 14400; src = w2; dst = w2bc; K = 2048; N = 32; tn = 0; tk = bid; srcld = N_SSM; }
    __shared__ float tile[32][33];
    const int nb = tn * 32, kb = tk * 32;
    const int tx = threadIdx.x & 31, ty = threadIdx.x >> 5;
    #pragma unroll
    for (int i = 0; i < 32; i += 8) {
        int k = kb + ty + i, n = nb + tx;
        tile[ty + i][tx] = (k < K && n < N) ? src[(size_t)k * srcld + n] : 0.f;
    }
    __syncthreads();
    #pragma unroll
    for (int i = 0; i < 32; i += 8) {
        int n = nb + ty + i, k = kb + tx;
        if (n < N && k < K) dst[(size_t)n * K + k] = __float2bfloat16(tile[tx][ty + i]);
    }
}

// ---------------- MFMA GEMM body (v6 schedule: 2-buf, 4 waves x 64x32, vmcnt(6)) ----
// C[M,N] = A[M,K](bf16) @ Wt[N,K](bf16)^T
// EPI: 0 = bf16 store (col<N guard), 1 = +bias softplus f32, 2 = f32 (atomic if at),
//      3 = cols<32 -> f32 sideband (ld 32), cols in [32,N) -> bf16
#define TM 128
#define TN 64
#define TK 64

template<int SWZ>
__device__ __forceinline__ void remap(int id, int NX, int& bx, int& by) {
    if (SWZ >= 0) {   // bind XCD (id&7) to a contiguous 2^SWZ range of n-tiles
        int xcd = id & 7, slot = id >> 3;
        bx = (xcd << SWZ) + (slot & ((1 << SWZ) - 1));
        by = slot >> SWZ;
    } else { bx = id % NX; by = id / NX; }
}

template<int EPI>
__device__ __forceinline__ void gemm_body(
    bf16* AsB, bf16* BsB, int bx, int by,
    const bf16* __restrict__ A, int lda,
    const bf16* __restrict__ Wt, int ldw,
    float* __restrict__ Cf, bf16* __restrict__ Cb, int ldc,
    const float* __restrict__ bias,
    int N, int K, int kbeg, int Kc, bool at)
{
    const int tid = threadIdx.x;
    const int wave = tid >> 6, lane = tid & 63;
    const int wm = (wave >> 1) * 64, wn = (wave & 1) * 32;
    const int m0 = by * TM, n0 = bx * TN;
    const int lm = lane & 15, kq = lane >> 4;

    // staging: lane covers row (lane>>3), swizzled chunk (lane&7)^row
    const int srow = lane >> 3;
    const int schunk = (lane & 7) ^ srow;
    const bf16* gA = A + (size_t)(m0 + wave * 32 + srow) * lda + schunk * 8;
    const bf16* gB = Wt + (size_t)(n0 + wave * 16 + srow) * ldw + schunk * 8;

    const int NK = Kc / TK;   // even
    f32x4 acc[4][2] = {};
    const int fsw = (lm & 7);   // frag-read XOR key

    auto stage = [&](int buf, int it) {
        const int k0 = kbeg + it * TK;
        bf16* lA = AsB + buf * (TM * TK) + (wave * 32) * TK;
        bf16* lB = BsB + buf * (TN * TK) + (wave * 16) * TK;
        #pragma unroll
        for (int g = 0; g < 4; ++g)
            load16_lds(gA + (size_t)(8 * g) * lda + k0, lA + (8 * g) * TK);
        #pragma unroll
        for (int g = 0; g < 2; ++g)
            load16_lds(gB + (size_t)(8 * g) * ldw + k0, lB + (8 * g) * TK);
    };
    auto compute = [&](int buf) {
        const bf16* Asb = AsB + buf * (TM * TK);
        const bf16* Bsb = BsB + buf * (TN * TK);
        bf16x8 af[4][2], bfr[2][2];
        #pragma unroll
        for (int i = 0; i < 4; ++i)
            #pragma unroll
            for (int t = 0; t < 2; ++t)
                af[i][t] = *(const bf16x8*)(&Asb[(wm + i * 16 + lm) * TK + ((t * 4 + kq) ^ fsw) * 8]);
        #pragma unroll
        for (int j = 0; j < 2; ++j)
            #pragma unroll
            for (int t = 0; t < 2; ++t)
                bfr[j][t] = *(const bf16x8*)(&Bsb[(wn + j * 16 + lm) * TK + ((t * 4 + kq) ^ fsw) * 8]);
        #pragma unroll
        for (int t = 0; t < 2; ++t)
            #pragma unroll
            for (int i = 0; i < 4; ++i)
                #pragma unroll
                for (int j = 0; j < 2; ++j)
                    acc[i][j] = __builtin_amdgcn_mfma_f32_16x16x32_bf16(af[i][t], bfr[j][t], acc[i][j], 0, 0, 0);
    };

    stage(0, 0);                                  // 6 loads in flight
    for (int it = 0; it < NK; it += 2) {
        stage(1, it + 1);                         // 12 in flight
        __builtin_amdgcn_s_waitcnt(0x0F76);       // vmcnt(6): buf0 done, buf1 flying
        __builtin_amdgcn_s_barrier();
        compute(0);
        __builtin_amdgcn_s_barrier();             // everyone done reading buf0
        if (it + 2 < NK) {
            stage(0, it + 2);
            __builtin_amdgcn_s_waitcnt(0x0F76);   // buf1 done, buf0 flying
        } else {
            __builtin_amdgcn_s_waitcnt(0x0F70);   // vmcnt(0)
        }
        __builtin_amdgcn_s_barrier();
        compute(1);
        __builtin_amdgcn_s_barrier();
    }

    // D layout: col = lane&15, row = (lane>>4)*4 + r (m89-verified)
    #pragma unroll
    for (int i = 0; i < 4; ++i) {
        #pragma unroll
        for (int j = 0; j < 2; ++j) {
            int gcol = n0 + wn + j * 16 + lm;
            if ((EPI == 0 || EPI == 3) && gcol >= N) continue;
            #pragma unroll
            for (int r = 0; r < 4; ++r) {
                int grow = m0 + wm + i * 16 + kq * 4 + r;
                float v = acc[i][j][r];
                if (EPI == 1) {
                    v += bias[gcol];
                    v = (v > 20.f) ? v : log1pf(__expf(v));
                    Cf[(size_t)grow * ldc + gcol] = v;
                } else if (EPI == 2) {
                    if (at) atomicAdd(&Cf[(size_t)grow * ldc + gcol], v);
                    else    Cf[(size_t)grow * ldc + gcol] = v;
                } else if (EPI == 3) {
                    if (gcol < 32) Cf[(size_t)grow * 32 + gcol] = v;     // f32 sideband
                    else           Cb[(size_t)grow * ldc + gcol] = __float2bfloat16(v);
                } else {
                    Cb[(size_t)grow * ldc + gcol] = __float2bfloat16(v);
                }
            }
        }
    }
}

// single-GEMM wrapper (2D grid + optional split-K over z)
template<int EPI, int KSPLIT = 1, int SWZ = -1>
__global__ __launch_bounds__(256) void mfma_gemm(
    const bf16* __restrict__ A, int lda,
    const bf16* __restrict__ Wt, int ldw,
    float* __restrict__ Cf, bf16* __restrict__ Cb, int ldc,
    const float* __restrict__ bias,
    int N, int K)
{
    __shared__ __align__(16) bf16 As[2][TM * TK];
    __shared__ __align__(16) bf16 Bs[2][TN * TK];
    int bx, by;
    if (SWZ >= 0) {
        int id = blockIdx.x + (int)(gridDim.x * blockIdx.y);
        remap<SWZ>(id, gridDim.x, bx, by);
    } else { bx = blockIdx.x; by = blockIdx.y; }
    const int Kc = K / KSPLIT;
    const int kbeg = (KSPLIT > 1) ? blockIdx.z * Kc : 0;
    gemm_body<EPI>(&As[0][0], &Bs[0][0], bx, by, A, lda, Wt, ldw, Cf, Cb, ldc,
                   bias, N, K, kbeg, Kc, KSPLIT > 1);
}

// dual-GEMM: two independent GEMMs in ONE launch (fills residency rounds, kills tails)
template<int EPI0, int SWZ0, int EPI1, int SWZ1>
__global__ __launch_bounds__(256) void mfma_gemm_dual(
    int nblk0, int NX0,
    const bf16* __restrict__ A0, int lda0, const bf16* __restrict__ Wt0, int ldw0,
    float* __restrict__ Cf0, bf16* __restrict__ Cb0, int ldc0,
    const float* __restrict__ bias0, int N0, int K0,
    int NX1,
    const bf16* __restrict__ A1, int lda1, const bf16* __restrict__ Wt1, int ldw1,
    float* __restrict__ Cf1, bf16* __restrict__ Cb1, int ldc1,
    const float* __restrict__ bias1, int N1, int K1)
{
    __shared__ __align__(16) bf16 As[2][TM * TK];
    __shared__ __align__(16) bf16 Bs[2][TN * TK];
    int id = blockIdx.x;
    if (id < nblk0) {
        int bx, by; remap<SWZ0>(id, NX0, bx, by);
        gemm_body<EPI0>(&As[0][0], &Bs[0][0], bx, by, A0, lda0, Wt0, ldw0,
                        Cf0, Cb0, ldc0, bias0, N0, K0, 0, K0, false);
    } else {
        id -= nblk0;
        int bx, by; remap<SWZ1>(id, NX1, bx, by);
        gemm_body<EPI1>(&As[0][0], &Bs[0][0], bx, by, A1, lda1, Wt1, ldw1,
                        Cf1, Cb1, ldc1, bias1, N1, K1, 0, K1, false);
    }
}

// ---------------- depthwise causal conv (k=4) + bias + SiLU (bf16 io, 8 ch/thread) ----
__global__ void conv_silu_kernel(const bf16* __restrict__ xz,
                                 const float* __restrict__ conv_w,
                                 const float* __restrict__ conv_b,
                                 bf16* __restrict__ u)
{
    int idx = blockIdx.x * blockDim.x + threadIdx.x;   // over BB*LL*DINNER/8
    int d8 = idx & (DINNER / 8 - 1);
    int l  = (idx >> 8) & (LL - 1);
    int b  = idx >> 18;
    int d0 = d8 * 8;

    float acc[8];
    {
        float4 b0 = *(const float4*)(conv_b + d0);
        float4 b1 = *(const float4*)(conv_b + d0 + 4);
        acc[0] = b0.x; acc[1] = b0.y; acc[2] = b0.z; acc[3] = b0.w;
        acc[4] = b1.x; acc[5] = b1.y; acc[6] = b1.z; acc[7] = b1.w;
    }
    #pragma unroll
    for (int j = 0; j < DCONV; ++j) {
        int ll = l - (DCONV - 1) + j;
        if (ll >= 0) {
            bf16x8 v = *(const bf16x8*)(xz + ((size_t)(b * LL + ll)) * N_XZ + d0);
            #pragma unroll
            for (int r = 0; r < 8; ++r) {
                float xv = __uint_as_float(((unsigned)(unsigned short)v[r]) << 16);
                acc[r] = fmaf(conv_w[(d0 + r) * DCONV + j], xv, acc[r]);
            }
        }
    }
    bf16x8 out;
    #pragma unroll
    for (int r = 0; r < 8; ++r) {
        float y = acc[r] / (1.f + __expf(-acc[r]));
        bf16 h = __float2bfloat16(y);
        out[r] = *reinterpret_cast<short*>(&h);
    }
    *(bf16x8*)(u + ((size_t)(b * LL + l)) * DINNER + d0) = out;
}

// ---------------- scan phase A: lane per (b,d,chunk), h[16] in regs ----------------
__global__ __launch_bounds__(256) void scan_phase_a(
    const float* __restrict__ dt, const bf16* __restrict__ u,
    const float* __restrict__ BC,    // (B,L,32) f32: B=[0:16), C=[16:32)
    const float* __restrict__ A_log,
    float* __restrict__ chunkP, float* __restrict__ chunkH)
{
    const int d = blockIdx.x * 256 + threadIdx.x;
    const int c = blockIdx.y, b = blockIdx.z;
    const int l0 = c * LCH;

    float A[DSTATE];
    {
        const f32x4* ap = (const f32x4*)(A_log + d * DSTATE);
        #pragma unroll
        for (int q = 0; q < 4; ++q) {
            f32x4 v = ap[q];
            #pragma unroll
            for (int r = 0; r < 4; ++r) A[q * 4 + r] = -__expf(v[r]);
        }
    }
    float h[DSTATE];
    #pragma unroll
    for (int n = 0; n < DSTATE; ++n) h[n] = 0.f;
    float sdt = 0.f;

    const float* dtp = dt + ((size_t)b * LL + l0) * DINNER + d;
    const bf16* up = u + ((size_t)b * LL + l0) * DINNER + d;
    const float* bcp = BC + ((size_t)b * LL + l0) * 32;

    #pragma unroll 2
    for (int i = 0; i < LCH; ++i) {
        float dtv = *dtp;
        float uv  = (float)*up;
        float du  = dtv * uv;
        f32x4 Bv[4];
        #pragma unroll
        for (int q = 0; q < 4; ++q) Bv[q] = *(const f32x4*)(bcp + q * 4);
        #pragma unroll
        for (int n = 0; n < DSTATE; ++n) {
            float a = __expf(dtv * A[n]);
            h[n] = fmaf(a, h[n], du * Bv[n >> 2][n & 3]);
        }
        sdt += dtv;
        dtp += DINNER; up += DINNER; bcp += 32;
    }

    size_t idx = (((size_t)b * CCH + c) * DINNER + d) * DSTATE;
    #pragma unroll
    for (int q = 0; q < 4; ++q) {
        f32x4 pv, hv;
        #pragma unroll
        for (int r = 0; r < 4; ++r) { pv[r] = __expf(A[q * 4 + r] * sdt); hv[r] = h[q * 4 + r]; }
        *(f32x4*)(chunkP + idx + q * 4) = pv;
        *(f32x4*)(chunkH + idx + q * 4) = hv;
    }
}

// ---------------- scan phase P: exclusive prefix over chunks, in place on chunkH ----
__global__ __launch_bounds__(256) void scan_phase_p(
    const float* __restrict__ chunkP, float* __restrict__ chunkH)
{
    int gid = blockIdx.x * 256 + threadIdx.x;   // over B*DINNER*DSTATE = 65536
    int n = gid & 15;
    int d = (gid >> 4) & (DINNER - 1);
    int b = gid >> 15;
    const size_t stride = (size_t)DINNER * DSTATE;
    size_t idx = ((size_t)b * CCH * DINNER + d) * DSTATE + n;
    float H = 0.f;
    for (int c = 0; c < CCH; ++c) {
        float P  = chunkP[idx];
        float hl = chunkH[idx];
        chunkH[idx] = H;           // exclusive prefix
        H = fmaf(P, H, hl);
        idx += stride;
    }
}

// ---------------- scan phase B: lane per (b,d,chunk); gated y over u --------
__global__ __launch_bounds__(256) void scan_phase_b(
    const float* __restrict__ dt, bf16* __restrict__ u,
    const float* __restrict__ BC, const bf16* __restrict__ xz,
    const float* __restrict__ A_log, const float* __restrict__ Dp,
    const float* __restrict__ chunkH)
{
    const int d = blockIdx.x * 256 + threadIdx.x;
    const int c = blockIdx.y, b = blockIdx.z;
    const int l0 = c * LCH;

    float A[DSTATE];
    {
        const f32x4* ap = (const f32x4*)(A_log + d * DSTATE);
        #pragma unroll
        for (int q = 0; q < 4; ++q) {
            f32x4 v = ap[q];
            #pragma unroll
            for (int r = 0; r < 4; ++r) A[q * 4 + r] = -__expf(v[r]);
        }
    }
    const float Dd = Dp[d];
    float h[DSTATE];
    {
        size_t idx = (((size_t)b * CCH + c) * DINNER + d) * DSTATE;
        #pragma unroll
        for (int q = 0; q < 4; ++q) {
            f32x4 v = *(const f32x4*)(chunkH + idx + q * 4);
            #pragma unroll
            for (int r = 0; r < 4; ++r) h[q * 4 + r] = v[r];
        }
    }

    const float* dtp = dt + ((size_t)b * LL + l0) * DINNER + d;
    bf16* up = u + ((size_t)b * LL + l0) * DINNER + d;
    const float* bcp = BC + ((size_t)b * LL + l0) * 32;
    const bf16* zp = xz + ((size_t)b * LL + l0) * N_XZ + DINNER + d;

    #pragma unroll 2
    for (int i = 0; i < LCH; ++i) {
        float dtv = *dtp;
        float uv  = (float)*up;
        float du  = dtv * uv;
        f32x4 Bv[4], Cv[4];
        #pragma unroll
        for (int q = 0; q < 4; ++q) {
            Bv[q] = *(const f32x4*)(bcp + q * 4);
            Cv[q] = *(const f32x4*)(bcp + 16 + q * 4);
        }
        float acc = 0.f;
        #pragma unroll
        for (int n = 0; n < DSTATE; ++n) {
            float a = __expf(dtv * A[n]);
            h[n] = fmaf(a, h[n], du * Bv[n >> 2][n & 3]);
            acc = fmaf(h[n], Cv[n >> 2][n & 3], acc);
        }
        float zv = (float)*zp;
        acc = fmaf(Dd, uv, acc);
        acc *= zv / (1.f + __expf(-zv));
        *up = __float2bfloat16(acc);
        dtp += DINNER; up += DINNER; bcp += 32; zp += N_XZ;
    }
}

extern "C" void kernel_launch(void* const* d_in, const int* in_sizes, int n_in,
                              void* d_out, int out_size, void* d_ws, size_t ws_size,
                              hipStream_t stream) {
    const float* x         = (const float*)d_in[0];
    const float* in_proj_w = (const float*)d_in[1];
    const float* conv_w    = (const float*)d_in[2];
    const float* conv_b    = (const float*)d_in[3];
    const float* x_proj_w  = (const float*)d_in[4];
    const float* dt_proj_w = (const float*)d_in[5];
    const float* dt_proj_b = (const float*)d_in[6];
    const float* A_log     = (const float*)d_in[7];
    const float* Dp        = (const float*)d_in[8];
    const float* out_proj_w= (const float*)d_in[9];
    float* out = (float*)d_out;

    // workspace layout (~80.7 MB, unchanged total); xbf aliases dt;
    // wft reuses the old ssm slot; chunkP aliases Wt1; chunkH aliases w2slot.
    char* p = (char*)d_ws;
    float* dt   = (float*)p;                          p += (size_t)MM * DINNER * 4;       // 16.8 MB
    bf16*  xbf  = (bf16*)dt;
    bf16*  xz   = (bf16*)p;                           p += (size_t)MM * N_XZ * 2;         // 16.8 MB
    bf16*  u    = (bf16*)p;                           p += (size_t)MM * DINNER * 2;       // 8.4 MB
    bf16*  wft  = (bf16*)p;                           p += (size_t)MM * N_SSM * 2;        // slot 8.5 MB (Wf^T uses 8.4)
    bf16*  Wt1  = (bf16*)p;                           p += (size_t)N_XZ * DMODEL * 2;     // 8.4 MB
    bf16*  w2slot = (bf16*)p;                         p += (size_t)N_SSM_PAD * DINNER * 2;// 8.9 MB
    bf16*  W2bf = w2slot;                             // 2048x2080 bf16 = 8.52 MB
    bf16*  w2bc = w2slot + (size_t)DINNER * N_SSM;    // 32x2048 bf16 = 131 KB (slot tail)
    bf16*  Wt3  = (bf16*)p;                           p += (size_t)DINNER * DINNER * 2;   // 8.4 MB
    bf16*  Wt4  = (bf16*)p;                           p += (size_t)DMODEL * DINNER * 2;   // 4.2 MB
    float* BC   = (float*)p;                          p += (size_t)MM * 32 * 4;           // 256 KB
    float* chunkP = (float*)Wt1;     // 8.4 MB (Wt1 dead after megaA)
    float* chunkH = (float*)w2slot;  // 8.4 MB (W2bf dead after megaA; w2bc is past 8.52MB)

    // 0) prep: W1/W3/W4 transposes + W2 cvt + W2[:, :32] transpose + x cvt
    prep_kernel<<<16512, 256, 0, stream>>>(x, xbf, in_proj_w, Wt1, dt_proj_w, Wt3,
                                           out_proj_w, Wt4, x_proj_w, W2bf, w2bc);
    // 1) megaA (1536 blocks = 2 full residency rounds):
    //    sub0: xz = xbf @ W1t      (2048x4096, K=1024)  1024 blocks, SWZ=3
    //    sub1: Wf^T = W3t @ W2dt   (2048x2048, K=2048)   512 blocks, SWZ=2
    //          Wf^T[j,i] = sum_k W3[k,j] * W2[i,32+k]  (A=Wt3, Wt=W2bf+32 ld 2080)
    mfma_gemm_dual<0, 3, 0, 2><<<1536, 256, 0, stream>>>(
        1024, 64, xbf, DMODEL, Wt1, DMODEL, nullptr, xz, N_XZ, nullptr, N_XZ, DMODEL,
        32, Wt3, DINNER, W2bf + 32, N_SSM, nullptr, wft, DINNER, nullptr, DINNER, DINNER);
    // 2) u = silu(conv(x_inner)+b)
    {
        int n = BB * LL * DINNER / 8;
        conv_silu_kernel<<<(n + 255) / 256, 256, 0, stream>>>(xz, conv_w, conv_b, u);
    }
    // 3) megaB (528 blocks):
    //    sub0: dt = softplus(u @ Wf + b)  (2048x2048, K=2048)  512 blocks, EPI=1, SWZ=2
    //    sub1: BC = u @ W2[:, :32]        (2048x32,  K=2048)    16 blocks, EPI=3
    mfma_gemm_dual<1, 2, 3, -1><<<528, 256, 0, stream>>>(
        512, 32, u, DINNER, wft, DINNER, dt, nullptr, DINNER, dt_proj_b, DINNER, DINNER,
        1, u, DINNER, w2bc, DINNER, BC, nullptr, 32, nullptr, 32, DINNER);
    // 4) chunked selective scan: A (local), P (prefix), B (apply; y over u)
    scan_phase_a<<<dim3(DINNER / 256, CCH, BB), 256, 0, stream>>>(dt, u, BC, A_log, chunkP, chunkH);
    scan_phase_p<<<dim3(BB * DINNER * DSTATE / 256), 256, 0, stream>>>(chunkP, chunkH);
    scan_phase_b<<<dim3(DINNER / 256, CCH, BB), 256, 0, stream>>>(dt, u, BC, xz, A_log, Dp, chunkH);
    // 5) out = y @ W4   (2048x1024, K=2048), split-K=4 atomic — 1024 blocks, SWZ=1
    hipMemsetAsync(out, 0, (size_t)out_size * sizeof(float), stream);
    mfma_gemm<2, 4, 1><<<dim3(DMODEL / TN, MM / TM, 4), 256, 0, stream>>>(
        u, DINNER, Wt4, DINNER, out, nullptr, DMODEL, nullptr, DMODEL, DINNER);
}